// Round 3
// baseline (28145.853 us; speedup 1.0000x reference)
//
#include <hip/hip_runtime.h>

#define NOP   2048
#define NACT  1024
#define NB    32
#define NBLK  256
#define NTHR  256

typedef _Float16 f16;
typedef _Float16 h2t __attribute__((ext_vector_type(2)));
typedef unsigned long long u64t;
typedef unsigned int u32t;

// ---------- helpers ----------

template <int CTRL>
__device__ __forceinline__ float dpp_add(float x) {
  union { float f; int i; } a, r;
  a.f = x;
  r.i = __builtin_amdgcn_update_dpp(0, a.i, CTRL, 0xF, 0xF, true);
  return x + r.f;
}

// full 64-lane sum; total lands in lane 63 (VALU-only)
__device__ __forceinline__ float wave_sum63(float x) {
  x = dpp_add<0x111>(x);  // row_shr:1
  x = dpp_add<0x112>(x);  // row_shr:2
  x = dpp_add<0x114>(x);  // row_shr:4
  x = dpp_add<0x118>(x);  // row_shr:8
  x = dpp_add<0x142>(x);  // row_bcast15
  x = dpp_add<0x143>(x);  // row_bcast31 -> lane63 = total
  return x;
}

__device__ __forceinline__ float dot8(float4 wv, float4 hv, float acc) {
  union U { float f; h2t v; };
  U w0{wv.x}, w1{wv.y}, w2{wv.z}, w3{wv.w};
  U h0{hv.x}, h1{hv.y}, h2{hv.z}, h3{hv.w};
#if __has_builtin(__builtin_amdgcn_fdot2)
  acc = __builtin_amdgcn_fdot2(w0.v, h0.v, acc, false);
  acc = __builtin_amdgcn_fdot2(w1.v, h1.v, acc, false);
  acc = __builtin_amdgcn_fdot2(w2.v, h2.v, acc, false);
  acc = __builtin_amdgcn_fdot2(w3.v, h3.v, acc, false);
#else
  acc += (float)w0.v.x * (float)h0.v.x + (float)w0.v.y * (float)h0.v.y;
  acc += (float)w1.v.x * (float)h1.v.x + (float)w1.v.y * (float)h1.v.y;
  acc += (float)w2.v.x * (float)h2.v.x + (float)w2.v.y * (float)h2.v.y;
  acc += (float)w3.v.x * (float)h3.v.x + (float)w3.v.y * (float)h3.v.y;
#endif
  return acc;
}

__device__ __forceinline__ float sigmoid_f(float x) {
  return 1.0f / (1.0f + __expf(-x));
}
__device__ __forceinline__ float tanh_f(float x) {
  float ax = fabsf(x);
  float e = __expf(-2.0f * ax);
  float r = (1.0f - e) / (1.0f + e);
  return copysignf(r, x);
}

// ---------- prep: pack W_hh (f32) -> fp16 ----------
// chunk tid = b*8192 + w*2048 + r*256 + c*64 + l  (16B chunks)
// wave-local row r = gate*2 + jj ; global row = gate*NOP + b*8 + w*2 + jj
// k = l*32 + c*8
extern "C" __global__ __launch_bounds__(256) void prep_pack(
    const float* __restrict__ Whh, f16* __restrict__ Wp) {
  int tid = blockIdx.x * 256 + threadIdx.x;  // 2M chunks
  int l = tid & 63;
  int c = (tid >> 6) & 3;
  int r = (tid >> 8) & 7;
  int w = (tid >> 11) & 3;
  int b = tid >> 13;
  int gate = r >> 1, jj = r & 1;
  int grow = gate * NOP + b * 8 + w * 2 + jj;
  int k = l * 32 + c * 8;
  const float4* src = (const float4*)(Whh + (size_t)grow * NOP + k);
  float4 a = src[0], b2 = src[1];
  union { f16 h[8]; float4 v; } o;
  o.h[0] = (f16)a.x;  o.h[1] = (f16)a.y;  o.h[2] = (f16)a.z;  o.h[3] = (f16)a.w;
  o.h[4] = (f16)b2.x; o.h[5] = (f16)b2.y; o.h[6] = (f16)b2.z; o.h[7] = (f16)b2.w;
  ((float4*)Wp)[tid] = o.v;
}

// ---------- persistent LSTM kernel (barrier-free waves) ----------
// 256 blocks x 4 waves. Wave w of block b owns elements {b*8+2w, b*8+2w+1}
// and their 4 gate rows. Exchange: push-based private mailboxes.
// mailbox[c] = 2048 u64 slots (2 parities x 1024); slot s=b*4+w holds
// {tag=t+1 (lo32) | 2xf16 h-pair (hi32)} for h(t), parity t&1.
extern "C" __global__ void __launch_bounds__(NTHR) lstm_main(
    const float* __restrict__ Wih, const float* __restrict__ bih,
    const float* __restrict__ bhh, const f16* __restrict__ Wp,
    float* __restrict__ outputs, u64t* __restrict__ tagged) {
  extern __shared__ char smem[];
  f16* w_lds = (f16*)smem;  // [w:4][r:8][c:4][lane:64][8 halves] = 128 KiB

  const int b  = blockIdx.x;
  const int w  = threadIdx.x >> 6;
  const int ln = threadIdx.x & 63;

  {  // stage this wave's 32 KiB of weights (wave-local, no barrier needed)
    const float4* src = (const float4*)(Wp + (size_t)b * 65536) + w * 2048;
    float4* dst = (float4*)w_lds + w * 2048;
    for (int i = ln; i < 2048; i += 64) dst[i] = src[i];
  }

  // x_gates for this wave's 8 rows (result valid in lane 63 only)
  float xg[8];
#pragma unroll
  for (int r = 0; r < 8; ++r) {
    int gate = r >> 1, jj = r & 1;
    int grow = gate * NOP + b * 8 + w * 2 + jj;
    const float4* src = (const float4*)(Wih + (size_t)grow * NOP) + ln * 8;
    float s = 0.f;
#pragma unroll
    for (int q = 0; q < 8; ++q) {
      float4 v = src[q];
      s += v.x + v.y + v.z + v.w;
    }
    s = wave_sum63(s);
    xg[r] = s * (1.0f / NOP) + bih[grow] + bhh[grow];
  }

  float c0 = 0.f, c1 = 0.f;  // cell state (lane 63's values are the real ones)
  const int slot_id = b * 4 + w;

  for (int t = 0; t < NACT; ++t) {
    float S[8];
    if (t > 0) {
      // poll own mailbox: 16 contiguous slots = this lane's k-slice (one line)
      const u64t* base = tagged + (size_t)b * 2048 +
                         (size_t)((t - 1) & 1) * 1024 + ln * 16;
      const u32t want = (u32t)t;
      u64t x[16];
      for (;;) {
        bool good = true;
#pragma unroll
        for (int i = 0; i < 16; ++i)
          x[i] = __hip_atomic_load(base + i, __ATOMIC_RELAXED,
                                   __HIP_MEMORY_SCOPE_AGENT);
#pragma unroll
        for (int i = 0; i < 16; ++i) good &= ((u32t)x[i] == want);
        if (__all(good)) break;
      }
      union PF { u32t u; float f; };
      float4 hreg[4];
#pragma unroll
      for (int c = 0; c < 4; ++c) {
        PF p0, p1, p2, p3;
        p0.u = (u32t)(x[c * 4 + 0] >> 32);
        p1.u = (u32t)(x[c * 4 + 1] >> 32);
        p2.u = (u32t)(x[c * 4 + 2] >> 32);
        p3.u = (u32t)(x[c * 4 + 3] >> 32);
        hreg[c] = make_float4(p0.f, p1.f, p2.f, p3.f);
      }
#pragma unroll
      for (int r = 0; r < 8; ++r) {
        float acc = 0.f;
#pragma unroll
        for (int c = 0; c < 4; ++c) {
          float4 wv = *((const float4*)(
              w_lds + (((((w * 8 + r) * 4) + c) * 64 + ln) * 8)));
          acc = dot8(wv, hreg[c], acc);
        }
        S[r] = wave_sum63(acc) + xg[r];
      }
    } else {
#pragma unroll
      for (int r = 0; r < 8; ++r) S[r] = xg[r];  // h(0)=0
    }

    // gates + state update (all lanes compute; lane 63 holds the true values)
    float i0 = sigmoid_f(S[0]), i1 = sigmoid_f(S[1]);
    float f0 = sigmoid_f(S[2]), f1 = sigmoid_f(S[3]);
    float g0 = tanh_f(S[4]),    g1 = tanh_f(S[5]);
    float o0 = sigmoid_f(S[6]), o1 = sigmoid_f(S[7]);
    c0 = f0 * c0 + i0 * g0;
    c1 = f1 * c1 + i1 * g1;
    float h0 = o0 * tanh_f(c0);
    float h1 = o1 * tanh_f(c1);

    // publish FIRST (critical path), outputs store after
    union { f16 q[2]; u32t u; } pk;
    pk.q[0] = (f16)h0; pk.q[1] = (f16)h1;
    u32t pair = (u32t)__shfl((int)pk.u, 63);
    if (t < NACT - 1) {
      u64t val = ((u64t)pair << 32) | (u64t)(u32t)(t + 1);
      size_t slot = (size_t)slot_id + (size_t)(t & 1) * 1024;
#pragma unroll
      for (int q = 0; q < 4; ++q)
        __hip_atomic_store(tagged + (size_t)(ln + q * 64) * 2048 + slot, val,
                           __ATOMIC_RELAXED, __HIP_MEMORY_SCOPE_AGENT);
    }
    if (ln == 63) {
      float2 hv; hv.x = h0; hv.y = h1;
      *((float2*)(outputs + (size_t)t * NOP + b * 8 + w * 2)) = hv;
    }
  }
}

// ---------- phase 2: entropy + reinforce ----------
extern "C" __global__ __launch_bounds__(256) void phase2(
    const float* __restrict__ outputs, const float* __restrict__ rewards,
    const int* __restrict__ action, float* __restrict__ accum) {
  __shared__ float sm[4], s1s[4], s2s[4];
  __shared__ float bc[2];
  const int t = blockIdx.x, tid = threadIdx.x, w = tid >> 6, ln = tid & 63;
  const float* row = outputs + (size_t)t * NOP;
  const float4* r4 = (const float4*)row;
  float4 a = r4[tid], b4 = r4[tid + 256];

  float m = fmaxf(fmaxf(fmaxf(a.x, a.y), fmaxf(a.z, a.w)),
                  fmaxf(fmaxf(b4.x, b4.y), fmaxf(b4.z, b4.w)));
#pragma unroll
  for (int off = 32; off >= 1; off >>= 1) m = fmaxf(m, __shfl_xor(m, off));
  if (ln == 0) sm[w] = m;
  __syncthreads();
  if (tid == 0) bc[0] = fmaxf(fmaxf(sm[0], sm[1]), fmaxf(sm[2], sm[3]));
  __syncthreads();
  const float M = bc[0];

  float s1 = 0.f, s2 = 0.f;
  {
    float xs[8] = {a.x, a.y, a.z, a.w, b4.x, b4.y, b4.z, b4.w};
#pragma unroll
    for (int u = 0; u < 8; ++u) {
      float d = xs[u] - M;
      float p = __expf(d);
      s1 += p;
      s2 += d * p;
    }
  }
#pragma unroll
  for (int off = 32; off >= 1; off >>= 1) {
    s1 += __shfl_xor(s1, off);
    s2 += __shfl_xor(s2, off);
  }
  if (ln == 0) { s1s[w] = s1; s2s[w] = s2; }
  __syncthreads();
  if (tid == 0) {
    float S1 = s1s[0] + s1s[1] + s1s[2] + s1s[3];
    float S2 = s2s[0] + s2s[1] + s2s[2] + s2s[3];
    float lse = M + logf(S1);
    atomicAdd(&accum[1], logf(S1) - S2 / S1);  // entropy of this row
    bc[1] = lse;
  }
  __syncthreads();
  if (tid < 32) {  // tid == batch index
    int ai = action[tid * NACT + t] & (NOP - 1);
    float val = row[ai] - bc[1];
    float rr = rewards[tid] * val;
#pragma unroll
    for (int off = 16; off >= 1; off >>= 1) rr += __shfl_xor(rr, off);
    if (tid == 0) atomicAdd(&accum[0], rr);
  }
}

extern "C" __global__ void finalize(const float* __restrict__ accum,
                                    float* __restrict__ out) {
  out[0] = accum[1] - accum[0] * (1.0f / NB);
}

// ---------- launch ----------
extern "C" void kernel_launch(void* const* d_in, const int* in_sizes, int n_in,
                              void* d_out, int out_size, void* d_ws, size_t ws_size,
                              hipStream_t stream) {
  const float* W_ih    = (const float*)d_in[0];
  const float* W_hh    = (const float*)d_in[1];
  const float* b_ih    = (const float*)d_in[2];
  const float* b_hh    = (const float*)d_in[3];
  const float* rewards = (const float*)d_in[4];
  const int*   action  = (const int*)d_in[5];

  char* ws = (char*)d_ws;
  u64t*  tagged  = (u64t*)ws;                         // [0, 4 MiB): 256 mailboxes x 16 KiB
  float* accum   = (float*)(ws + 4u * 1024 * 1024);   // small
  float* outputs = (float*)(ws + 8u * 1024 * 1024);   // [8, 16 MiB)
  f16*   Wp      = (f16*)(ws + 16u * 1024 * 1024);    // [16, 48 MiB)

  hipMemsetAsync(accum, 0, 256, stream);

  hipLaunchKernelGGL(prep_pack, dim3(8192), dim3(256), 0, stream, W_hh, Wp);

  const unsigned smem = 131072;  // weights only
  hipFuncSetAttribute((const void*)lstm_main,
                      hipFuncAttributeMaxDynamicSharedMemorySize, (int)smem);
  void* args[] = {(void*)&W_ih, (void*)&b_ih, (void*)&b_hh,
                  (void*)&Wp, (void*)&outputs, (void*)&tagged};
  hipLaunchCooperativeKernel((void*)lstm_main, dim3(NBLK), dim3(NTHR), args,
                             smem, stream);

  hipLaunchKernelGGL(phase2, dim3(NACT), dim3(256), 0, stream,
                     outputs, rewards, action, accum);
  hipLaunchKernelGGL(finalize, dim3(1), dim3(1), 0, stream, accum, (float*)d_out);
}

// Round 5
// 4656.257 us; speedup vs baseline: 6.0447x; 6.0447x over previous
//
#include <hip/hip_runtime.h>

#define NOP   2048
#define NACT  1024
#define NB    32
#define NBLK  256
#define NTHR  320   // 4 worker waves + 1 aggregator wave (active in blocks 0..7)

typedef _Float16 f16;
typedef _Float16 h2t __attribute__((ext_vector_type(2)));
typedef unsigned long long u64t;
typedef unsigned int u32t;

// ---------- helpers ----------

template <int CTRL>
__device__ __forceinline__ float dpp_add(float x) {
  union { float f; int i; } a, r;
  a.f = x;
  r.i = __builtin_amdgcn_update_dpp(0, a.i, CTRL, 0xF, 0xF, true);
  return x + r.f;
}

// full 64-lane sum; total lands in lane 63 (VALU-only)
__device__ __forceinline__ float wave_sum63(float x) {
  x = dpp_add<0x111>(x);  // row_shr:1
  x = dpp_add<0x112>(x);  // row_shr:2
  x = dpp_add<0x114>(x);  // row_shr:4
  x = dpp_add<0x118>(x);  // row_shr:8
  x = dpp_add<0x142>(x);  // row_bcast15
  x = dpp_add<0x143>(x);  // row_bcast31 -> lane63 = total
  return x;
}

__device__ __forceinline__ float dot8(float4 wv, float4 hv, float acc) {
  union U { float f; h2t v; };
  U w0{wv.x}, w1{wv.y}, w2{wv.z}, w3{wv.w};
  U h0{hv.x}, h1{hv.y}, h2{hv.z}, h3{hv.w};
#if __has_builtin(__builtin_amdgcn_fdot2)
  acc = __builtin_amdgcn_fdot2(w0.v, h0.v, acc, false);
  acc = __builtin_amdgcn_fdot2(w1.v, h1.v, acc, false);
  acc = __builtin_amdgcn_fdot2(w2.v, h2.v, acc, false);
  acc = __builtin_amdgcn_fdot2(w3.v, h3.v, acc, false);
#else
  acc += (float)w0.v.x * (float)h0.v.x + (float)w0.v.y * (float)h0.v.y;
  acc += (float)w1.v.x * (float)h1.v.x + (float)w1.v.y * (float)h1.v.y;
  acc += (float)w2.v.x * (float)h2.v.x + (float)w2.v.y * (float)h2.v.y;
  acc += (float)w3.v.x * (float)h3.v.x + (float)w3.v.y * (float)h3.v.y;
#endif
  return acc;
}

__device__ __forceinline__ float sigmoid_f(float x) {
  return 1.0f / (1.0f + __expf(-x));
}
__device__ __forceinline__ float tanh_f(float x) {
  float ax = fabsf(x);
  float e = __expf(-2.0f * ax);
  float r = (1.0f - e) / (1.0f + e);
  return copysignf(r, x);
}

// monotone LDS-counter barrier for the 4 worker waves (aggregator not involved)
__device__ __forceinline__ void lds_bar(int* ctr, int target, int ln) {
  __threadfence_block();
  if (ln == 0)
    __hip_atomic_fetch_add(ctr, 1, __ATOMIC_RELAXED, __HIP_MEMORY_SCOPE_WORKGROUP);
  while (__hip_atomic_load(ctr, __ATOMIC_RELAXED, __HIP_MEMORY_SCOPE_WORKGROUP) <
         target) {}
  __threadfence_block();
}

// ---------- prep: pack W_hh (f32) -> fp16 ----------
// chunk tid = b*8192 + w*2048 + r*256 + c*64 + l  (16B chunks of 8 halves)
// wave-local row r = gate*2 + jj ; global row = gate*NOP + b*8 + w*2 + jj
// k = l*32 + c*8
extern "C" __global__ __launch_bounds__(256) void prep_pack(
    const float* __restrict__ Whh, f16* __restrict__ Wp) {
  int tid = blockIdx.x * 256 + threadIdx.x;  // 2M chunks
  int l = tid & 63;
  int c = (tid >> 6) & 3;
  int r = (tid >> 8) & 7;
  int w = (tid >> 11) & 3;
  int b = tid >> 13;
  int gate = r >> 1, jj = r & 1;
  int grow = gate * NOP + b * 8 + w * 2 + jj;
  int k = l * 32 + c * 8;
  const float4* src = (const float4*)(Whh + (size_t)grow * NOP + k);
  float4 a = src[0], b2 = src[1];
  union { f16 h[8]; float4 v; } o;
  o.h[0] = (f16)a.x;  o.h[1] = (f16)a.y;  o.h[2] = (f16)a.z;  o.h[3] = (f16)a.w;
  o.h[4] = (f16)b2.x; o.h[5] = (f16)b2.y; o.h[6] = (f16)b2.z; o.h[7] = (f16)b2.w;
  ((float4*)Wp)[tid] = o.v;
}

// ---------- persistent LSTM kernel ----------
// 256 blocks x 5 waves. Wave w (w<4) of block b owns elements {b*8+2w, +1} and
// all 4 of their gate rows; publishes ONE tagged u64 slot s=4b+w per step:
// {2xf16 h-pair (hi32) | tag=t+1 (lo32)}, 2 parity regions.
// Aggregator waves (wave4 of blocks 0..7): poll 128 contiguous slots coalesced,
// release an 8B flag when complete (windowed compare -> lag-proof, poison-proof).
// Workers: poll the 64B flag line (cheap), then ONE coalesced bulk read,
// verify tags (repair loop doubles as the no-aggregator fallback).
extern "C" __global__ void __launch_bounds__(NTHR) lstm_main(
    const float* __restrict__ Wih, const float* __restrict__ bih,
    const float* __restrict__ bhh, const f16* __restrict__ Wp,
    float* __restrict__ outputs, u64t* __restrict__ glob,
    u64t* __restrict__ sumf) {
  extern __shared__ char smem[];
  f16*  w_lds = (f16*)smem;                     // 128 KiB [w][r:8][c:4][l:64][8]
  u32t* h2    = (u32t*)(smem + 131072);         // 2 parities x 1148 words
  int*  barA  = (int*)(smem + 131072 + 9184);

  const int b  = blockIdx.x;
  const int w  = threadIdx.x >> 6;
  const int ln = threadIdx.x & 63;

  if (threadIdx.x == 0) *barA = 0;

  if (w < 4) {  // stage this wave's 32 KiB of weights (wave-local)
    const float4* src = (const float4*)(Wp + (size_t)b * 65536) + w * 2048;
    float4* dst = (float4*)w_lds + w * 2048;
    for (int i = ln; i < 2048; i += 64) dst[i] = src[i];
  }
  __syncthreads();  // barA init visible; only barrier in this kernel

  if (w == 4) {
    if (b >= 8) return;
    // ---- aggregator: 128 slots [b*128, b*128+128), coalesced 1 KiB sweeps ----
    for (int tau = 1; tau < NACT; ++tau) {
      const int par = (tau - 1) & 1;
      const u64t* src = glob + (size_t)par * 1024 + b * 128 + ln * 2;
      const u32t want = (u32t)tau;
      for (;;) {
        u64t x0 = __hip_atomic_load(src + 0, __ATOMIC_RELAXED, __HIP_MEMORY_SCOPE_AGENT);
        u64t x1 = __hip_atomic_load(src + 1, __ATOMIC_RELAXED, __HIP_MEMORY_SCOPE_AGENT);
        // windowed: tag in [want, want+4] passes (lag-proof); poison fails
        bool good = (((u32t)x0 - want) <= 4u) & (((u32t)x1 - want) <= 4u);
        if (__all(good)) break;
      }
      if (ln == 0)
        __hip_atomic_store(&sumf[par * 8 + b], (u64t)want,
                           __ATOMIC_RELEASE, __HIP_MEMORY_SCOPE_AGENT);
    }
    return;
  }

  // ---- worker waves ----
  float xg[8];  // x_gates for this wave's 8 rows (valid in lane 63)
#pragma unroll
  for (int r = 0; r < 8; ++r) {
    int gate = r >> 1, jj = r & 1;
    int grow = gate * NOP + b * 8 + w * 2 + jj;
    const float4* src = (const float4*)(Wih + (size_t)grow * NOP) + ln * 8;
    float s = 0.f;
#pragma unroll
    for (int q = 0; q < 8; ++q) {
      float4 v = src[q];
      s += v.x + v.y + v.z + v.w;
    }
    s = wave_sum63(s);
    xg[r] = s * (1.0f / NOP) + bih[grow] + bhh[grow];
  }

  float c0 = 0.f, c1 = 0.f;  // lane 63's values are the real ones

  for (int t = 0; t < NACT; ++t) {
    float S[8];
    if (t > 0) {
      const int par = (t - 1) & 1;
      const u32t want = (u32t)t;
      {  // flag wait: one 64B line, 8 lanes; capped spins -> fallback
        int spins = 0;
        for (;;) {
          bool ok = true;
          if (ln < 8) {
            u64t fv = __hip_atomic_load(&sumf[par * 8 + ln], __ATOMIC_RELAXED,
                                        __HIP_MEMORY_SCOPE_AGENT);
            ok = (((u32t)fv - want) <= 4u);
          }
          if (__all(ok)) break;
          if (++spins > 2048) break;  // aggregator dead/slow -> direct poll below
        }
      }
      // bulk read (coalesced: lane ln -> 32B at byte offset 32*ln) + verify
      const u64t* base = glob + (size_t)par * 1024 + w * 256 + ln * 4;
      u64t x0, x1, x2, x3;
      for (;;) {
        x0 = __hip_atomic_load(base + 0, __ATOMIC_RELAXED, __HIP_MEMORY_SCOPE_AGENT);
        x1 = __hip_atomic_load(base + 1, __ATOMIC_RELAXED, __HIP_MEMORY_SCOPE_AGENT);
        x2 = __hip_atomic_load(base + 2, __ATOMIC_RELAXED, __HIP_MEMORY_SCOPE_AGENT);
        x3 = __hip_atomic_load(base + 3, __ATOMIC_RELAXED, __HIP_MEMORY_SCOPE_AGENT);
        bool good = ((u32t)x0 == want) & ((u32t)x1 == want) &
                    ((u32t)x2 == want) & ((u32t)x3 == want);
        if (__all(good)) break;
      }
      // scatter payloads to LDS. uint4-slot Q=64w+ln -> padded P=Q+Q/8
      // (injective, 16B aligned, bank-uniform for both write and read)
      uint4* hp4 = (uint4*)(h2 + par * 1148);
      {
        uint4 pay;
        pay.x = (u32t)(x0 >> 32); pay.y = (u32t)(x1 >> 32);
        pay.z = (u32t)(x2 >> 32); pay.w = (u32t)(x3 >> 32);
        int Q = 64 * w + ln;
        hp4[Q + (Q >> 3)] = pay;
      }
      lds_bar(barA, 4 * t, ln);  // all 4 waves' quarters present

      // gather k-slice: lane ln wants uint4-slots 4ln+c (h elems 32ln+8c..+7)
      float4 hreg[4];
#pragma unroll
      for (int c = 0; c < 4; ++c) {
        int Q = 4 * ln + c;
        hreg[c] = *((const float4*)hp4 + (Q + (Q >> 3)));
      }
#pragma unroll
      for (int r = 0; r < 8; ++r) {
        float acc = 0.f;
#pragma unroll
        for (int c = 0; c < 4; ++c) {
          float4 wv = *((const float4*)(
              w_lds + (((((w * 8 + r) * 4) + c) * 64 + ln) * 8)));
          acc = dot8(wv, hreg[c], acc);
        }
        S[r] = wave_sum63(acc) + xg[r];
      }
    } else {
#pragma unroll
      for (int r = 0; r < 8; ++r) S[r] = xg[r];  // h(0)=0
    }

    // gates + state update (lane 63 holds the true values)
    float i0 = sigmoid_f(S[0]), i1 = sigmoid_f(S[1]);
    float f0 = sigmoid_f(S[2]), f1 = sigmoid_f(S[3]);
    float g0 = tanh_f(S[4]),    g1 = tanh_f(S[5]);
    float o0 = sigmoid_f(S[6]), o1 = sigmoid_f(S[7]);
    c0 = f0 * c0 + i0 * g0;
    c1 = f1 * c1 + i1 * g1;
    float h0 = o0 * tanh_f(c0);
    float h1 = o1 * tanh_f(c1);

    if (ln == 63) {
      if (t < NACT - 1) {  // publish FIRST (critical path)
        union { f16 q[2]; u32t u; } pk;
        pk.q[0] = (f16)h0; pk.q[1] = (f16)h1;
        u64t val = ((u64t)pk.u << 32) | (u64t)(u32t)(t + 1);
        __hip_atomic_store(glob + (size_t)(t & 1) * 1024 + 4 * b + w, val,
                           __ATOMIC_RELAXED, __HIP_MEMORY_SCOPE_AGENT);
      }
      float2 hv; hv.x = h0; hv.y = h1;
      *((float2*)(outputs + (size_t)t * NOP + b * 8 + w * 2)) = hv;
    }
  }
}

// ---------- phase 2: entropy + reinforce ----------
extern "C" __global__ __launch_bounds__(256) void phase2(
    const float* __restrict__ outputs, const float* __restrict__ rewards,
    const int* __restrict__ action, float* __restrict__ accum) {
  __shared__ float sm[4], s1s[4], s2s[4];
  __shared__ float bc[2];
  const int t = blockIdx.x, tid = threadIdx.x, w = tid >> 6, ln = tid & 63;
  const float* row = outputs + (size_t)t * NOP;
  const float4* r4 = (const float4*)row;
  float4 a = r4[tid], b4 = r4[tid + 256];

  float m = fmaxf(fmaxf(fmaxf(a.x, a.y), fmaxf(a.z, a.w)),
                  fmaxf(fmaxf(b4.x, b4.y), fmaxf(b4.z, b4.w)));
#pragma unroll
  for (int off = 32; off >= 1; off >>= 1) m = fmaxf(m, __shfl_xor(m, off));
  if (ln == 0) sm[w] = m;
  __syncthreads();
  if (tid == 0) bc[0] = fmaxf(fmaxf(sm[0], sm[1]), fmaxf(sm[2], sm[3]));
  __syncthreads();
  const float M = bc[0];

  float s1 = 0.f, s2 = 0.f;
  {
    float xs[8] = {a.x, a.y, a.z, a.w, b4.x, b4.y, b4.z, b4.w};
#pragma unroll
    for (int u = 0; u < 8; ++u) {
      float d = xs[u] - M;
      float p = __expf(d);
      s1 += p;
      s2 += d * p;
    }
  }
#pragma unroll
  for (int off = 32; off >= 1; off >>= 1) {
    s1 += __shfl_xor(s1, off);
    s2 += __shfl_xor(s2, off);
  }
  if (ln == 0) { s1s[w] = s1; s2s[w] = s2; }
  __syncthreads();
  if (tid == 0) {
    float S1 = s1s[0] + s1s[1] + s1s[2] + s1s[3];
    float S2 = s2s[0] + s2s[1] + s2s[2] + s2s[3];
    float lse = M + logf(S1);
    atomicAdd(&accum[1], logf(S1) - S2 / S1);  // entropy of this row
    bc[1] = lse;
  }
  __syncthreads();
  if (tid < 32) {  // tid == batch index
    int ai = action[tid * NACT + t] & (NOP - 1);
    float val = row[ai] - bc[1];
    float rr = rewards[tid] * val;
#pragma unroll
    for (int off = 16; off >= 1; off >>= 1) rr += __shfl_xor(rr, off);
    if (tid == 0) atomicAdd(&accum[0], rr);
  }
}

extern "C" __global__ void finalize(const float* __restrict__ accum,
                                    float* __restrict__ out) {
  out[0] = accum[1] - accum[0] * (1.0f / NB);
}

// ---------- launch ----------
extern "C" void kernel_launch(void* const* d_in, const int* in_sizes, int n_in,
                              void* d_out, int out_size, void* d_ws, size_t ws_size,
                              hipStream_t stream) {
  const float* W_ih    = (const float*)d_in[0];
  const float* W_hh    = (const float*)d_in[1];
  const float* b_ih    = (const float*)d_in[2];
  const float* b_hh    = (const float*)d_in[3];
  const float* rewards = (const float*)d_in[4];
  const int*   action  = (const int*)d_in[5];

  char* ws = (char*)d_ws;
  u64t*  glob    = (u64t*)ws;                         // 16 KiB: 2 parities x 1024 x 8B
  u64t*  sumf    = (u64t*)(ws + 16 * 1024);           // 2 parities x 8 flags
  float* accum   = (float*)(ws + 20 * 1024);          // 2 f32
  float* outputs = (float*)(ws + 8u * 1024 * 1024);   // [8, 16 MiB)
  f16*   Wp      = (f16*)(ws + 16u * 1024 * 1024);    // [16, 48 MiB)

  hipMemsetAsync(accum, 0, 256, stream);  // tags/flags rely on poison != window

  hipLaunchKernelGGL(prep_pack, dim3(8192), dim3(256), 0, stream, W_hh, Wp);

  const unsigned smem = 131072 + 9184 + 16;  // weights + h2(padded,2par) + barA
  hipFuncSetAttribute((const void*)lstm_main,
                      hipFuncAttributeMaxDynamicSharedMemorySize, (int)smem);
  void* args[] = {(void*)&W_ih, (void*)&b_ih, (void*)&b_hh, (void*)&Wp,
                  (void*)&outputs, (void*)&glob, (void*)&sumf};
  hipLaunchCooperativeKernel((void*)lstm_main, dim3(NBLK), dim3(NTHR), args,
                             smem, stream);

  hipLaunchKernelGGL(phase2, dim3(NACT), dim3(256), 0, stream,
                     outputs, rewards, action, accum);
  hipLaunchKernelGGL(finalize, dim3(1), dim3(1), 0, stream, accum, (float*)d_out);
}